// Round 1
// baseline (1377.751 us; speedup 1.0000x reference)
//
#include <hip/hip_runtime.h>
#include <stdint.h>

// ---------------- problem constants ----------------
#define T_TOKENS 4096
#define D_HID    2048
#define D_INT    4096
#define N_EXP    8
#define TOPK     4
#define NFLAT    (T_TOKENS*TOPK)      // 16384 routed pairs (constant sum over experts)
#define BM       128                  // M tile (rows of routed tokens)
#define MAXPAD   (NFLAT + N_EXP*BM)   // 17408 worst-case padded rows
#define MTILES   (MAXPAD/BM)          // 136 fixed M-tiles

// ---------------- ws layout (bytes) ----------------
#define OFF_XB   0ull                       // 4096*2048 bf16 = 16,777,216
#define OFF_ACT  16777216ull                // 17408*4096 bf16 = 142,606,336
#define OFF_PTOK 159383552ull               // 17408 int
#define OFF_PWT  159453184ull               // 17408 float
#define OFF_CNT  159522816ull               // 8 int
#define OFF_TOFF 159523072ull               // 8*256 int
#define OFF_SEG  159531264ull               // 9 int

typedef float f32x4  __attribute__((ext_vector_type(4)));
typedef short bf16x8 __attribute__((ext_vector_type(8)));

__device__ __forceinline__ unsigned short f2bf(float f) {
    unsigned int u = __float_as_uint(f);
    u += 0x7fffu + ((u >> 16) & 1u);      // RNE
    return (unsigned short)(u >> 16);
}

__device__ __forceinline__ void gload_lds16(const void* g, void* l) {
    __builtin_amdgcn_global_load_lds((const __attribute__((address_space(1))) void*)g,
                                     (__attribute__((address_space(3))) void*)l,
                                     16, 0, 0);
}

// ---------------- kernel 0: cast x -> bf16, zero out ----------------
__global__ void k_prep(const float* __restrict__ x, unsigned short* __restrict__ xb,
                       float* __restrict__ out) {
    int i = blockIdx.x * 256 + threadIdx.x;          // 0 .. 2M-1 (float4 units), exact grid
    float4 v = ((const float4*)x)[i];
    ushort4 h;
    h.x = f2bf(v.x); h.y = f2bf(v.y); h.z = f2bf(v.z); h.w = f2bf(v.w);
    ((ushort4*)xb)[i] = h;
    ((float4*)out)[i] = make_float4(0.f, 0.f, 0.f, 0.f);
}

// ---------------- routing: deterministic compaction ----------------
__global__ void k_count(const int* __restrict__ te, int* __restrict__ counts,
                        int* __restrict__ toff) {
    int e = blockIdx.x, t = threadIdx.x;
    int cnt = 0;
    int base = t * 64;
    for (int i = 0; i < 64; i++) cnt += (te[base + i] == e);
    __shared__ int s[256];
    s[t] = cnt; __syncthreads();
    int incl = cnt;
    for (int off = 1; off < 256; off <<= 1) {
        int tmp = (t >= off) ? s[t - off] : 0;
        __syncthreads();
        incl += tmp; s[t] = incl;
        __syncthreads();
    }
    toff[e * 256 + t] = incl - cnt;
    if (t == 255) counts[e] = incl;
}

__global__ void k_fill(const int* __restrict__ te, const float* __restrict__ tw,
                       const int* __restrict__ counts, const int* __restrict__ toff,
                       int* __restrict__ ptok, float* __restrict__ pwt, int* __restrict__ seg) {
    int e = blockIdx.x, t = threadIdx.x;
    int segs[9]; int a = 0;
    #pragma unroll
    for (int j = 0; j < 8; j++) { segs[j] = a; a += (counts[j] + BM - 1) & ~(BM - 1); }
    segs[8] = a;
    if (e == 0 && t == 0) { for (int j = 0; j < 9; j++) seg[j] = segs[j]; }
    int base = segs[e] + toff[e * 256 + t];
    int rank = 0;
    for (int i = t * 64; i < (t + 1) * 64; i++) {
        if (te[i] == e) { ptok[base + rank] = i >> 2; pwt[base + rank] = tw[i]; rank++; }
    }
    int cnt = counts[e], pc = (cnt + BM - 1) & ~(BM - 1);
    for (int i = cnt + t; i < pc; i += 256) { ptok[segs[e] + i] = -1; pwt[segs[e] + i] = 0.f; }
}

// ---------------- GEMM1: h = xg @ Wgu^T, act = silu(gate)*up ----------------
// tile: 128 rows x 64 inter-cols (=128 weight rows: 64 gate + 64 up), BK=64
__launch_bounds__(256, 2)
__global__ void k_gemm1(const unsigned short* __restrict__ xb, const float* __restrict__ wgu,
                        const int* __restrict__ ptok, const int* __restrict__ seg,
                        unsigned short* __restrict__ act) {
    __shared__ char lds[32768];
    char* lA = lds; char* lB = lds + 16384;
    int nb = blockIdx.x, mb = blockIdx.y;
    if (mb * BM >= seg[8]) return;
    int e = 0;
    #pragma unroll
    for (int j = 1; j < 8; j++) if (seg[j] <= mb * BM) e = j;
    int tid = threadIdx.x, w = tid >> 6, l = tid & 63;

    // A staging: global_load_lds gather, source pre-swizzled (chunk ^= row&7)
    const char* asrc[4]; char* adst[4];
    #pragma unroll
    for (int i = 0; i < 4; i++) {
        int row = w * 32 + i * 8 + (l >> 3);
        int tok = ptok[mb * BM + row]; if (tok < 0) tok = 0;
        int csrc = (l & 7) ^ (row & 7);
        asrc[i] = (const char*)(xb + (size_t)tok * D_HID + csrc * 8);
        adst[i] = lA + (w * 32 + i * 8) * 128;
    }
    // B staging: fp32 -> bf16 reg-stage, swizzled ds_write
    const float* bsrc[8]; int bdst[8];
    #pragma unroll
    for (int j = 0; j < 8; j++) {
        int flat = j * 1024 + tid * 4;
        int r = flat >> 6, c = flat & 63;
        size_t grow = (r < 64) ? (size_t)(nb * 64 + r) : (size_t)(D_INT + nb * 64 + (r - 64));
        bsrc[j] = wgu + (size_t)e * 2 * D_INT * D_HID + grow * D_HID + c;
        bdst[j] = r * 128 + ((c * 2) ^ ((r & 7) << 4));
    }

    f32x4 acc[2][8];
    #pragma unroll
    for (int m = 0; m < 2; m++)
        #pragma unroll
        for (int n = 0; n < 8; n++) acc[m][n] = (f32x4){0.f, 0.f, 0.f, 0.f};

    for (int k0 = 0; k0 < D_HID; k0 += 64) {
        #pragma unroll
        for (int i = 0; i < 4; i++) gload_lds16(asrc[i] + (size_t)k0 * 2, adst[i]);
        #pragma unroll
        for (int j = 0; j < 8; j++) {
            float4 v = *(const float4*)(bsrc[j] + k0);
            ushort4 h;
            h.x = f2bf(v.x); h.y = f2bf(v.y); h.z = f2bf(v.z); h.w = f2bf(v.w);
            *(ushort4*)(lB + bdst[j]) = h;
        }
        __syncthreads();
        #pragma unroll
        for (int kk = 0; kk < 2; kk++) {
            bf16x8 a[2], b[8];
            #pragma unroll
            for (int m = 0; m < 2; m++) {
                int row = w * 32 + m * 16 + (l & 15);
                int kb = kk * 64 + (l >> 4) * 16;
                a[m] = *(const bf16x8*)(lA + row * 128 + (kb ^ ((row & 7) << 4)));
            }
            #pragma unroll
            for (int n = 0; n < 8; n++) {
                int row = n * 16 + (l & 15);
                int kb = kk * 64 + (l >> 4) * 16;
                b[n] = *(const bf16x8*)(lB + row * 128 + (kb ^ ((row & 7) << 4)));
            }
            #pragma unroll
            for (int m = 0; m < 2; m++)
                #pragma unroll
                for (int n = 0; n < 8; n++)
                    acc[m][n] = __builtin_amdgcn_mfma_f32_16x16x32_bf16(a[m], b[n], acc[m][n], 0, 0, 0);
        }
        __syncthreads();
    }
    // epilogue: act = silu(gate) * up (gate = n 0..3, up = n 4..7)
    #pragma unroll
    for (int m = 0; m < 2; m++)
        #pragma unroll
        for (int n = 0; n < 4; n++) {
            f32x4 g = acc[m][n], u = acc[m][n + 4];
            #pragma unroll
            for (int r = 0; r < 4; r++) {
                float gv = g[r], uv = u[r];
                float av = gv / (1.f + __expf(-gv)) * uv;
                int row = w * 32 + m * 16 + (l >> 4) * 4 + r;
                int col = nb * 64 + n * 16 + (l & 15);
                act[(size_t)(mb * BM + row) * D_INT + col] = f2bf(av);
            }
        }
}

// ---------------- GEMM2: out[tok] += wt * (act @ Wd^T) ----------------
// tile: 128 rows x 128 out-cols, BK=64
__launch_bounds__(256, 2)
__global__ void k_gemm2(const unsigned short* __restrict__ act, const float* __restrict__ wd,
                        const int* __restrict__ ptok, const float* __restrict__ pwt,
                        const int* __restrict__ seg, float* __restrict__ out) {
    __shared__ char lds[32768];
    char* lA = lds; char* lB = lds + 16384;
    int nb = blockIdx.x, mb = blockIdx.y;
    if (mb * BM >= seg[8]) return;
    int e = 0;
    #pragma unroll
    for (int j = 1; j < 8; j++) if (seg[j] <= mb * BM) e = j;
    int tid = threadIdx.x, w = tid >> 6, l = tid & 63;

    const char* asrc[4]; char* adst[4];
    #pragma unroll
    for (int i = 0; i < 4; i++) {
        int row = w * 32 + i * 8 + (l >> 3);
        int csrc = (l & 7) ^ (row & 7);
        asrc[i] = (const char*)(act + (size_t)(mb * BM + row) * D_INT + csrc * 8);
        adst[i] = lA + (w * 32 + i * 8) * 128;
    }
    const float* bsrc[8]; int bdst[8];
    #pragma unroll
    for (int j = 0; j < 8; j++) {
        int flat = j * 1024 + tid * 4;
        int r = flat >> 6, c = flat & 63;
        bsrc[j] = wd + (size_t)e * D_HID * D_INT + (size_t)(nb * BM + r) * D_INT + c;
        bdst[j] = r * 128 + ((c * 2) ^ ((r & 7) << 4));
    }

    f32x4 acc[2][8];
    #pragma unroll
    for (int m = 0; m < 2; m++)
        #pragma unroll
        for (int n = 0; n < 8; n++) acc[m][n] = (f32x4){0.f, 0.f, 0.f, 0.f};

    for (int k0 = 0; k0 < D_INT; k0 += 64) {
        #pragma unroll
        for (int i = 0; i < 4; i++) gload_lds16(asrc[i] + (size_t)k0 * 2, adst[i]);
        #pragma unroll
        for (int j = 0; j < 8; j++) {
            float4 v = *(const float4*)(bsrc[j] + k0);
            ushort4 h;
            h.x = f2bf(v.x); h.y = f2bf(v.y); h.z = f2bf(v.z); h.w = f2bf(v.w);
            *(ushort4*)(lB + bdst[j]) = h;
        }
        __syncthreads();
        #pragma unroll
        for (int kk = 0; kk < 2; kk++) {
            bf16x8 a[2], b[8];
            #pragma unroll
            for (int m = 0; m < 2; m++) {
                int row = w * 32 + m * 16 + (l & 15);
                int kb = kk * 64 + (l >> 4) * 16;
                a[m] = *(const bf16x8*)(lA + row * 128 + (kb ^ ((row & 7) << 4)));
            }
            #pragma unroll
            for (int n = 0; n < 8; n++) {
                int row = n * 16 + (l & 15);
                int kb = kk * 64 + (l >> 4) * 16;
                b[n] = *(const bf16x8*)(lB + row * 128 + (kb ^ ((row & 7) << 4)));
            }
            #pragma unroll
            for (int m = 0; m < 2; m++)
                #pragma unroll
                for (int n = 0; n < 8; n++)
                    acc[m][n] = __builtin_amdgcn_mfma_f32_16x16x32_bf16(a[m], b[n], acc[m][n], 0, 0, 0);
        }
        __syncthreads();
    }
    // epilogue: scaled atomic accumulate into out[token]
    #pragma unroll
    for (int m = 0; m < 2; m++) {
        #pragma unroll
        for (int r = 0; r < 4; r++) {
            int row = w * 32 + m * 16 + (l >> 4) * 4 + r;
            int p = mb * BM + row;
            int tok = ptok[p];
            float wt = pwt[p];
            if (tok >= 0) {
                #pragma unroll
                for (int n = 0; n < 8; n++) {
                    int col = nb * BM + n * 16 + (l & 15);
                    unsafeAtomicAdd(&out[(size_t)tok * D_HID + col], wt * acc[m][n][r]);
                }
            }
        }
    }
}

extern "C" void kernel_launch(void* const* d_in, const int* in_sizes, int n_in,
                              void* d_out, int out_size, void* d_ws, size_t ws_size,
                              hipStream_t stream) {
    const float* x   = (const float*)d_in[0];
    const float* tw  = (const float*)d_in[2];
    const int*   te  = (const int*)d_in[3];
    const float* wgu = (const float*)d_in[4];
    const float* wd  = (const float*)d_in[5];
    float* out = (float*)d_out;
    char*  ws  = (char*)d_ws;

    unsigned short* xb  = (unsigned short*)(ws + OFF_XB);
    unsigned short* act = (unsigned short*)(ws + OFF_ACT);
    int*   ptok   = (int*)(ws + OFF_PTOK);
    float* pwt    = (float*)(ws + OFF_PWT);
    int*   counts = (int*)(ws + OFF_CNT);
    int*   toff   = (int*)(ws + OFF_TOFF);
    int*   seg    = (int*)(ws + OFF_SEG);

    k_prep<<<8192, 256, 0, stream>>>(x, xb, out);
    k_count<<<N_EXP, 256, 0, stream>>>(te, counts, toff);
    k_fill<<<N_EXP, 256, 0, stream>>>(te, tw, counts, toff, ptok, pwt, seg);
    k_gemm1<<<dim3(D_INT / 64, MTILES), 256, 0, stream>>>(xb, wgu, ptok, seg, act);
    k_gemm2<<<dim3(D_HID / BM, MTILES), 256, 0, stream>>>(act, wd, ptok, pwt, seg, out);
}

// Round 2
// 1208.758 us; speedup vs baseline: 1.1398x; 1.1398x over previous
//
#include <hip/hip_runtime.h>
#include <stdint.h>

// ---------------- problem constants ----------------
#define T_TOKENS 4096
#define D_HID    2048
#define D_INT    4096
#define N_EXP    8
#define TOPK     4
#define NFLAT    (T_TOKENS*TOPK)      // 16384 routed pairs
#define BM       128                  // M tile
#define MAXPAD   (NFLAT + N_EXP*BM)   // 17408 worst-case padded rows
#define MTILES   (MAXPAD/BM)          // 136 fixed M-tiles

// ---------------- ws layout (bytes) ----------------
#define OFF_PTOK 0ull                       // 17408*4 = 69632
#define OFF_PWT  69632ull                   // 69632
#define OFF_CNT  139264ull                  // 32
#define OFF_TOFF 139392ull                  // 8192
#define OFF_SEG  147584ull                  // 36
#define OFF_XB   262144ull                  // 4096*2048*2 = 16,777,216
#define OFF_ACT  17039360ull                // 17408*4096*2 = 142,606,336
#define OFF_WGU  159645696ull               // 8*8192*2048*2 = 268,435,456
#define OFF_WD   428081152ull               // 8*2048*4096*2 = 134,217,728
#define NEED_BF16 562298880ull

typedef float f32x4  __attribute__((ext_vector_type(4)));
typedef short bf16x8 __attribute__((ext_vector_type(8)));

__device__ __forceinline__ unsigned short f2bf(float f) {
    unsigned int u = __float_as_uint(f);
    u += 0x7fffu + ((u >> 16) & 1u);      // RNE
    return (unsigned short)(u >> 16);
}

__device__ __forceinline__ void gload_lds16(const void* g, void* l) {
    __builtin_amdgcn_global_load_lds((const __attribute__((address_space(1))) void*)g,
                                     (__attribute__((address_space(3))) void*)l,
                                     16, 0, 0);
}

// XCD-bijective chunk swizzle (m204): hw block id -> logical, contiguous per XCD
__device__ __forceinline__ int xcd_logical(int hw, int nwg) {
    int q = nwg >> 3, r = nwg & 7;
    int xc = hw & 7, sl = hw >> 3;
    return (xc < r ? xc * (q + 1) : r * (q + 1) + (xc - r) * q) + sl;
}

// ---------------- kernel 0: cast x -> bf16, zero out ----------------
__global__ void k_prep(const float* __restrict__ x, unsigned short* __restrict__ xb,
                       float* __restrict__ out) {
    int i = blockIdx.x * 256 + threadIdx.x;          // float4 units, exact grid (8192 blocks)
    float4 v = ((const float4*)x)[i];
    ushort4 h;
    h.x = f2bf(v.x); h.y = f2bf(v.y); h.z = f2bf(v.z); h.w = f2bf(v.w);
    ((ushort4*)xb)[i] = h;
    ((float4*)out)[i] = make_float4(0.f, 0.f, 0.f, 0.f);
}

// ---------------- kernel: weights fp32 -> bf16 (one pass) ----------------
__global__ void k_conv(const float* __restrict__ wgu, const float* __restrict__ wd,
                       unsigned short* __restrict__ wgu_b, unsigned short* __restrict__ wd_b) {
    size_t i = (size_t)blockIdx.x * 256 + threadIdx.x;   // float4 index
    const size_t NG4 = (size_t)N_EXP * 2 * D_INT * D_HID / 4;  // 33554432
    float4 v; unsigned short* dst;
    if (i < NG4) { v = ((const float4*)wgu)[i]; dst = wgu_b + i * 4; }
    else { size_t j = i - NG4; v = ((const float4*)wd)[j]; dst = wd_b + j * 4; }
    ushort4 h;
    h.x = f2bf(v.x); h.y = f2bf(v.y); h.z = f2bf(v.z); h.w = f2bf(v.w);
    *(ushort4*)dst = h;
}

// ---------------- routing: deterministic compaction ----------------
__global__ void k_count(const int* __restrict__ te, int* __restrict__ counts,
                        int* __restrict__ toff) {
    int e = blockIdx.x, t = threadIdx.x;
    int cnt = 0;
    int base = t * 64;
    for (int i = 0; i < 64; i++) cnt += (te[base + i] == e);
    __shared__ int s[256];
    s[t] = cnt; __syncthreads();
    int incl = cnt;
    for (int off = 1; off < 256; off <<= 1) {
        int tmp = (t >= off) ? s[t - off] : 0;
        __syncthreads();
        incl += tmp; s[t] = incl;
        __syncthreads();
    }
    toff[e * 256 + t] = incl - cnt;
    if (t == 255) counts[e] = incl;
}

__global__ void k_fill(const int* __restrict__ te, const float* __restrict__ tw,
                       const int* __restrict__ counts, const int* __restrict__ toff,
                       int* __restrict__ ptok, float* __restrict__ pwt, int* __restrict__ seg) {
    int e = blockIdx.x, t = threadIdx.x;
    int segs[9]; int a = 0;
    #pragma unroll
    for (int j = 0; j < 8; j++) { segs[j] = a; a += (counts[j] + BM - 1) & ~(BM - 1); }
    segs[8] = a;
    if (e == 0 && t == 0) { for (int j = 0; j < 9; j++) seg[j] = segs[j]; }
    int base = segs[e] + toff[e * 256 + t];
    int rank = 0;
    for (int i = t * 64; i < (t + 1) * 64; i++) {
        if (te[i] == e) { ptok[base + rank] = i >> 2; pwt[base + rank] = tw[i]; rank++; }
    }
    int cnt = counts[e], pc = (cnt + BM - 1) & ~(BM - 1);
    for (int i = cnt + t; i < pc; i += 256) { ptok[segs[e] + i] = -1; pwt[segs[e] + i] = 0.f; }
}

// ---------------- GEMM1: h = xg @ Wgu^T, act = silu(gate)*up ----------------
// tile: 128 rows x 64 inter-cols (=128 weight rows: 64 gate + 64 up), BK=64
template<bool BF16W>
__launch_bounds__(256, 2)
__global__ void k_gemm1(const unsigned short* __restrict__ xb, const void* __restrict__ wguv,
                        const int* __restrict__ ptok, const int* __restrict__ seg,
                        unsigned short* __restrict__ act) {
    __shared__ char lds[32768];
    char* lA = lds; char* lB = lds + 16384;
    int logical = xcd_logical(blockIdx.x, gridDim.x);
    int nb = logical / MTILES, mb = logical % MTILES;
    if (mb * BM >= seg[8]) return;
    int e = 0;
    #pragma unroll
    for (int j = 1; j < 8; j++) if (seg[j] <= mb * BM) e = j;
    int tid = threadIdx.x, w = tid >> 6, l = tid & 63;

    // A staging: global_load_lds, source pre-swizzled (chunk ^= row&7)
    const char* asrc[4]; char* adst[4];
    #pragma unroll
    for (int i = 0; i < 4; i++) {
        int row = w * 32 + i * 8 + (l >> 3);
        int tok = ptok[mb * BM + row]; if (tok < 0) tok = 0;
        int csrc = (l & 7) ^ (row & 7);
        asrc[i] = (const char*)(xb + (size_t)tok * D_HID + csrc * 8);
        adst[i] = lA + (w * 32 + i * 8) * 128;
    }

    // B staging
    const unsigned short* bsrc16[4]; char* bdst16[4];
    const float* bsrc32[8]; int bdst32[8];
    if constexpr (BF16W) {
        const unsigned short* wb = (const unsigned short*)wguv + (size_t)e * 2 * D_INT * D_HID;
        #pragma unroll
        for (int i = 0; i < 4; i++) {
            int rrow = w * 32 + i * 8 + (l >> 3);
            size_t grow = (rrow < 64) ? (size_t)(nb * 64 + rrow)
                                      : (size_t)(D_INT + nb * 64 + (rrow - 64));
            int csrc = (l & 7) ^ (rrow & 7);
            bsrc16[i] = wb + grow * D_HID + csrc * 8;
            bdst16[i] = lB + (w * 32 + i * 8) * 128;
        }
    } else {
        const float* wgu = (const float*)wguv;
        #pragma unroll
        for (int j = 0; j < 8; j++) {
            int flat = j * 1024 + tid * 4;
            int r = flat >> 6, c = flat & 63;
            size_t grow = (r < 64) ? (size_t)(nb * 64 + r) : (size_t)(D_INT + nb * 64 + (r - 64));
            bsrc32[j] = wgu + (size_t)e * 2 * D_INT * D_HID + grow * D_HID + c;
            bdst32[j] = r * 128 + ((c * 2) ^ ((r & 7) << 4));
        }
    }

    f32x4 acc[2][8];
    #pragma unroll
    for (int m = 0; m < 2; m++)
        #pragma unroll
        for (int n = 0; n < 8; n++) acc[m][n] = (f32x4){0.f, 0.f, 0.f, 0.f};

    for (int k0 = 0; k0 < D_HID; k0 += 64) {
        #pragma unroll
        for (int i = 0; i < 4; i++) gload_lds16(asrc[i] + (size_t)k0 * 2, adst[i]);
        if constexpr (BF16W) {
            #pragma unroll
            for (int i = 0; i < 4; i++) gload_lds16(bsrc16[i] + k0, bdst16[i]);
        } else {
            #pragma unroll
            for (int j = 0; j < 8; j++) {
                float4 v = *(const float4*)(bsrc32[j] + k0);
                ushort4 h;
                h.x = f2bf(v.x); h.y = f2bf(v.y); h.z = f2bf(v.z); h.w = f2bf(v.w);
                *(ushort4*)(lB + bdst32[j]) = h;
            }
        }
        __syncthreads();
        #pragma unroll
        for (int kk = 0; kk < 2; kk++) {
            bf16x8 a[2], b[8];
            #pragma unroll
            for (int m = 0; m < 2; m++) {
                int row = w * 32 + m * 16 + (l & 15);
                int kb = kk * 64 + (l >> 4) * 16;
                a[m] = *(const bf16x8*)(lA + row * 128 + (kb ^ ((row & 7) << 4)));
            }
            #pragma unroll
            for (int n = 0; n < 8; n++) {
                int row = n * 16 + (l & 15);
                int kb = kk * 64 + (l >> 4) * 16;
                b[n] = *(const bf16x8*)(lB + row * 128 + (kb ^ ((row & 7) << 4)));
            }
            #pragma unroll
            for (int m = 0; m < 2; m++)
                #pragma unroll
                for (int n = 0; n < 8; n++)
                    acc[m][n] = __builtin_amdgcn_mfma_f32_16x16x32_bf16(a[m], b[n], acc[m][n], 0, 0, 0);
        }
        __syncthreads();
    }
    // epilogue: act = silu(gate) * up (gate = n 0..3, up = n 4..7)
    #pragma unroll
    for (int m = 0; m < 2; m++)
        #pragma unroll
        for (int n = 0; n < 4; n++) {
            f32x4 g = acc[m][n], u = acc[m][n + 4];
            #pragma unroll
            for (int r = 0; r < 4; r++) {
                float gv = g[r], uv = u[r];
                float av = gv / (1.f + __expf(-gv)) * uv;
                int row = w * 32 + m * 16 + (l >> 4) * 4 + r;
                int col = nb * 64 + n * 16 + (l & 15);
                act[(size_t)(mb * BM + row) * D_INT + col] = f2bf(av);
            }
        }
}

// ---------------- GEMM2: out[tok] += wt * (act @ Wd^T) ----------------
// tile: 128 rows x 128 out-cols, BK=64
template<bool BF16W>
__launch_bounds__(256, 2)
__global__ void k_gemm2(const unsigned short* __restrict__ act, const void* __restrict__ wdv,
                        const int* __restrict__ ptok, const float* __restrict__ pwt,
                        const int* __restrict__ seg, float* __restrict__ out) {
    __shared__ char lds[32768];
    char* lA = lds; char* lB = lds + 16384;
    int logical = xcd_logical(blockIdx.x, gridDim.x);
    int nb = logical / MTILES, mb = logical % MTILES;
    if (mb * BM >= seg[8]) return;
    int e = 0;
    #pragma unroll
    for (int j = 1; j < 8; j++) if (seg[j] <= mb * BM) e = j;
    int tid = threadIdx.x, w = tid >> 6, l = tid & 63;

    const char* asrc[4]; char* adst[4];
    #pragma unroll
    for (int i = 0; i < 4; i++) {
        int row = w * 32 + i * 8 + (l >> 3);
        int csrc = (l & 7) ^ (row & 7);
        asrc[i] = (const char*)(act + (size_t)(mb * BM + row) * D_INT + csrc * 8);
        adst[i] = lA + (w * 32 + i * 8) * 128;
    }
    const unsigned short* bsrc16[4]; char* bdst16[4];
    const float* bsrc32[8]; int bdst32[8];
    if constexpr (BF16W) {
        const unsigned short* wb = (const unsigned short*)wdv + (size_t)e * D_HID * D_INT;
        #pragma unroll
        for (int i = 0; i < 4; i++) {
            int rrow = w * 32 + i * 8 + (l >> 3);
            int csrc = (l & 7) ^ (rrow & 7);
            bsrc16[i] = wb + (size_t)(nb * BM + rrow) * D_INT + csrc * 8;
            bdst16[i] = lB + (w * 32 + i * 8) * 128;
        }
    } else {
        const float* wd = (const float*)wdv;
        #pragma unroll
        for (int j = 0; j < 8; j++) {
            int flat = j * 1024 + tid * 4;
            int r = flat >> 6, c = flat & 63;
            bsrc32[j] = wd + (size_t)e * D_HID * D_INT + (size_t)(nb * BM + r) * D_INT + c;
            bdst32[j] = r * 128 + ((c * 2) ^ ((r & 7) << 4));
        }
    }

    f32x4 acc[2][8];
    #pragma unroll
    for (int m = 0; m < 2; m++)
        #pragma unroll
        for (int n = 0; n < 8; n++) acc[m][n] = (f32x4){0.f, 0.f, 0.f, 0.f};

    for (int k0 = 0; k0 < D_INT; k0 += 64) {
        #pragma unroll
        for (int i = 0; i < 4; i++) gload_lds16(asrc[i] + (size_t)k0 * 2, adst[i]);
        if constexpr (BF16W) {
            #pragma unroll
            for (int i = 0; i < 4; i++) gload_lds16(bsrc16[i] + k0, bdst16[i]);
        } else {
            #pragma unroll
            for (int j = 0; j < 8; j++) {
                float4 v = *(const float4*)(bsrc32[j] + k0);
                ushort4 h;
                h.x = f2bf(v.x); h.y = f2bf(v.y); h.z = f2bf(v.z); h.w = f2bf(v.w);
                *(ushort4*)(lB + bdst32[j]) = h;
            }
        }
        __syncthreads();
        #pragma unroll
        for (int kk = 0; kk < 2; kk++) {
            bf16x8 a[2], b[8];
            #pragma unroll
            for (int m = 0; m < 2; m++) {
                int row = w * 32 + m * 16 + (l & 15);
                int kb = kk * 64 + (l >> 4) * 16;
                a[m] = *(const bf16x8*)(lA + row * 128 + (kb ^ ((row & 7) << 4)));
            }
            #pragma unroll
            for (int n = 0; n < 8; n++) {
                int row = n * 16 + (l & 15);
                int kb = kk * 64 + (l >> 4) * 16;
                b[n] = *(const bf16x8*)(lB + row * 128 + (kb ^ ((row & 7) << 4)));
            }
            #pragma unroll
            for (int m = 0; m < 2; m++)
                #pragma unroll
                for (int n = 0; n < 8; n++)
                    acc[m][n] = __builtin_amdgcn_mfma_f32_16x16x32_bf16(a[m], b[n], acc[m][n], 0, 0, 0);
        }
        __syncthreads();
    }
    // epilogue: scaled atomic accumulate into out[token]
    #pragma unroll
    for (int m = 0; m < 2; m++) {
        #pragma unroll
        for (int r = 0; r < 4; r++) {
            int row = w * 32 + m * 16 + (l >> 4) * 4 + r;
            int p = mb * BM + row;
            int tok = ptok[p];
            float wt = pwt[p];
            if (tok >= 0) {
                #pragma unroll
                for (int n = 0; n < 8; n++) {
                    int col = nb * BM + n * 16 + (l & 15);
                    unsafeAtomicAdd(&out[(size_t)tok * D_HID + col], wt * acc[m][n][r]);
                }
            }
        }
    }
}

extern "C" void kernel_launch(void* const* d_in, const int* in_sizes, int n_in,
                              void* d_out, int out_size, void* d_ws, size_t ws_size,
                              hipStream_t stream) {
    const float* x   = (const float*)d_in[0];
    const float* tw  = (const float*)d_in[2];
    const int*   te  = (const int*)d_in[3];
    const float* wgu = (const float*)d_in[4];
    const float* wd  = (const float*)d_in[5];
    float* out = (float*)d_out;
    char*  ws  = (char*)d_ws;

    int*   ptok   = (int*)(ws + OFF_PTOK);
    float* pwt    = (float*)(ws + OFF_PWT);
    int*   counts = (int*)(ws + OFF_CNT);
    int*   toff   = (int*)(ws + OFF_TOFF);
    int*   seg    = (int*)(ws + OFF_SEG);
    unsigned short* xb    = (unsigned short*)(ws + OFF_XB);
    unsigned short* act   = (unsigned short*)(ws + OFF_ACT);
    unsigned short* wgu_b = (unsigned short*)(ws + OFF_WGU);
    unsigned short* wd_b  = (unsigned short*)(ws + OFF_WD);

    k_prep<<<8192, 256, 0, stream>>>(x, xb, out);
    k_count<<<N_EXP, 256, 0, stream>>>(te, counts, toff);
    k_fill<<<N_EXP, 256, 0, stream>>>(te, tw, counts, toff, ptok, pwt, seg);

    if (ws_size >= NEED_BF16) {
        k_conv<<<196608, 256, 0, stream>>>(wgu, wd, wgu_b, wd_b);
        k_gemm1<true><<<(D_INT / 64) * MTILES, 256, 0, stream>>>(xb, wgu_b, ptok, seg, act);
        k_gemm2<true><<<(D_HID / BM) * MTILES, 256, 0, stream>>>(act, wd_b, ptok, pwt, seg, out);
    } else {
        k_gemm1<false><<<(D_INT / 64) * MTILES, 256, 0, stream>>>(xb, wgu, ptok, seg, act);
        k_gemm2<false><<<(D_HID / BM) * MTILES, 256, 0, stream>>>(act, wd, ptok, pwt, seg, out);
    }
}